// Round 1
// baseline (1606.494 us; speedup 1.0000x reference)
//
#include <hip/hip_runtime.h>
#include <math.h>

#define N_NODES 50000
#define N_EDGES 800000
#define EP (N_EDGES + N_NODES)   /* 850000 with self loops */
#define IN_CH 128
#define HID 64
#define HEADS 4
#define F1 (HEADS * HID)         /* 256 */
#define LAT 32
#define NEG 0.2f

__device__ __forceinline__ void atomicMaxF(float* addr, float val) {
    // order-preserving split: non-negative floats compare as ints,
    // negative floats compare reversed as unsigned
    if (val >= 0.0f) atomicMax((int*)addr, __float_as_int(val));
    else             atomicMin((unsigned int*)addr, __float_as_uint(val));
}

// ---------------- GEMM1: x(N,128) @ Wl/Wr(128,256) -> xl1, xr1 ----------------
__global__ __launch_bounds__(256) void gemm1(const float* __restrict__ x,
                                             const float* __restrict__ Wl,
                                             const float* __restrict__ Wr,
                                             float* __restrict__ xl,
                                             float* __restrict__ xr) {
    __shared__ float xs[64][132];     // 64 rows x 128 k, pad to 132 (16B-aligned)
    __shared__ float wls[128][64];
    __shared__ float wrs[128][64];
    int t = threadIdx.x;
    int row0 = blockIdx.x * 64;
    int col0 = blockIdx.y * 64;
    // stage x tile (64x128)
#pragma unroll
    for (int i = 0; i < 8; i++) {
        int f = t + i * 256;          // float4 index 0..2047
        int r = f >> 5;
        int k4 = (f & 31) << 2;
        float4 v = make_float4(0.f, 0.f, 0.f, 0.f);
        if (row0 + r < N_NODES)
            v = *(const float4*)(x + (size_t)(row0 + r) * IN_CH + k4);
        *(float4*)&xs[r][k4] = v;
    }
    // stage W tiles (128x64 each)
#pragma unroll
    for (int i = 0; i < 8; i++) {
        int f = t + i * 256;
        int k = f >> 4;
        int c4 = (f & 15) << 2;
        *(float4*)&wls[k][c4] = *(const float4*)(Wl + (size_t)k * F1 + col0 + c4);
        *(float4*)&wrs[k][c4] = *(const float4*)(Wr + (size_t)k * F1 + col0 + c4);
    }
    __syncthreads();
    int ty = t >> 4, tx = t & 15;
    int r0 = ty * 4, c0 = tx * 4;
    float accl[4][4] = {};
    float accr[4][4] = {};
    for (int k = 0; k < 128; k++) {
        float a[4];
#pragma unroll
        for (int i = 0; i < 4; i++) a[i] = xs[r0 + i][k];
        float4 bl = *(float4*)&wls[k][c0];
        float4 br = *(float4*)&wrs[k][c0];
#pragma unroll
        for (int i = 0; i < 4; i++) {
            accl[i][0] += a[i] * bl.x; accl[i][1] += a[i] * bl.y;
            accl[i][2] += a[i] * bl.z; accl[i][3] += a[i] * bl.w;
            accr[i][0] += a[i] * br.x; accr[i][1] += a[i] * br.y;
            accr[i][2] += a[i] * br.z; accr[i][3] += a[i] * br.w;
        }
    }
#pragma unroll
    for (int i = 0; i < 4; i++) {
        int r = row0 + r0 + i;
        if (r < N_NODES) {
            *(float4*)(xl + (size_t)r * F1 + col0 + c0) =
                make_float4(accl[i][0], accl[i][1], accl[i][2], accl[i][3]);
            *(float4*)(xr + (size_t)r * F1 + col0 + c0) =
                make_float4(accr[i][0], accr[i][1], accr[i][2], accr[i][3]);
        }
    }
}

// ---------------- init kernels ----------------
__global__ void init1(float* smax, float* denom) {
    int i = blockIdx.x * 256 + threadIdx.x;
    if (i < N_NODES * HEADS) { smax[i] = -3.0e38f; denom[i] = 0.f; }
}
__global__ void init2(float* smax, float* denom) {
    int i = blockIdx.x * 256 + threadIdx.x;
    if (i < N_NODES) { smax[i] = -3.0e38f; denom[i] = 0.f; }
}

// ---------------- L1 pass 1: per-edge scores + segment max ----------------
__global__ __launch_bounds__(256) void edge_max1(const float* __restrict__ xl,
                                                 const float* __restrict__ xr,
                                                 const int* __restrict__ ei,
                                                 const float* __restrict__ att,
                                                 float* __restrict__ score,
                                                 float* __restrict__ smax) {
    int lane = threadIdx.x & 63;
    long e = (long)blockIdx.x * 4 + (threadIdx.x >> 6);
    if (e >= EP) return;
    int s, d;
    if (e < N_EDGES) { s = ei[e]; d = ei[N_EDGES + e]; }
    else             { s = d = (int)(e - N_EDGES); }
    const float* pl = xl + (size_t)s * F1;
    const float* pr = xr + (size_t)d * F1;
    float sc[HEADS];
#pragma unroll
    for (int h = 0; h < HEADS; h++) {
        float v = pl[h * HID + lane] + pr[h * HID + lane];
        v = v > 0.f ? v : NEG * v;
        sc[h] = v * att[h * HID + lane];
    }
#pragma unroll
    for (int off = 32; off > 0; off >>= 1) {
#pragma unroll
        for (int h = 0; h < HEADS; h++) sc[h] += __shfl_xor(sc[h], off);
    }
    if (lane == 0) {
#pragma unroll
        for (int h = 0; h < HEADS; h++) {
            score[e * HEADS + h] = sc[h];
            atomicMaxF(&smax[(size_t)d * HEADS + h], sc[h]);
        }
    }
}

// ---------------- L1 pass 2: exp + segment sum ----------------
__global__ void edge_exp1(const int* __restrict__ ei, float* __restrict__ score,
                          const float* __restrict__ smax, float* __restrict__ denom) {
    long idx = (long)blockIdx.x * 256 + threadIdx.x;
    if (idx >= (long)EP * HEADS) return;
    long e = idx >> 2;
    int h = (int)(idx & 3);
    int d = (e < N_EDGES) ? ei[N_EDGES + e] : (int)(e - N_EDGES);
    float ex = expf(score[idx] - smax[(size_t)d * HEADS + h]);
    score[idx] = ex;
    atomicAdd(&denom[(size_t)d * HEADS + h], ex);
}

// ---------------- L1 pass 3: weighted scatter-add ----------------
__global__ __launch_bounds__(256) void edge_agg1(const float* __restrict__ xl,
                                                 const int* __restrict__ ei,
                                                 const float* __restrict__ score,
                                                 const float* __restrict__ denom,
                                                 float* __restrict__ out) {
    int lane = threadIdx.x & 63;
    long e = (long)blockIdx.x * 4 + (threadIdx.x >> 6);
    if (e >= EP) return;
    int s, d;
    if (e < N_EDGES) { s = ei[e]; d = ei[N_EDGES + e]; }
    else             { s = d = (int)(e - N_EDGES); }
    const float* pl = xl + (size_t)s * F1;
    float* po = out + (size_t)d * F1;
#pragma unroll
    for (int h = 0; h < HEADS; h++) {
        float alpha = score[e * HEADS + h] / denom[(size_t)d * HEADS + h];
        atomicAdd(&po[h * HID + lane], pl[h * HID + lane] * alpha);
    }
}

// ---------------- node: bias + ELU (in place) ----------------
__global__ void node_elu(float* __restrict__ h, const float* __restrict__ bias) {
    long i = (long)blockIdx.x * 256 + threadIdx.x;
    if (i >= (long)N_NODES * F1) return;
    float v = h[i] + bias[i & (F1 - 1)];
    h[i] = v > 0.f ? v : expm1f(v);
}

// ---------------- GEMM2: h(N,256) @ Wl2/Wr2(256,32) -> xl2, xr2 ----------------
__global__ __launch_bounds__(256) void gemm2(const float* __restrict__ h,
                                             const float* __restrict__ Wl,
                                             const float* __restrict__ Wr,
                                             float* __restrict__ xl2,
                                             float* __restrict__ xr2) {
    __shared__ float hs[8][256];
    int t = threadIdx.x;
    int row0 = blockIdx.x * 8;
#pragma unroll
    for (int i = 0; i < 2; i++) {
        int f = t + i * 256;          // float4 index 0..511
        int r = f >> 6;
        int k4 = (f & 63) << 2;
        float4 v = make_float4(0.f, 0.f, 0.f, 0.f);
        if (row0 + r < N_NODES)
            v = *(const float4*)(h + (size_t)(row0 + r) * F1 + k4);
        *(float4*)&hs[r][k4] = v;
    }
    __syncthreads();
    int c = t & 31, rl = t >> 5;
    float al = 0.f, ar = 0.f;
    for (int k = 0; k < F1; k++) {
        float hv = hs[rl][k];
        al += hv * Wl[k * LAT + c];
        ar += hv * Wr[k * LAT + c];
    }
    int r = row0 + rl;
    if (r < N_NODES) {
        xl2[(size_t)r * LAT + c] = al;
        xr2[(size_t)r * LAT + c] = ar;
    }
}

// ---------------- L2 pass 1: scores + segment max ----------------
__global__ __launch_bounds__(256) void edge_max2(const float* __restrict__ xl,
                                                 const float* __restrict__ xr,
                                                 const int* __restrict__ ei,
                                                 const float* __restrict__ att,
                                                 float* __restrict__ score,
                                                 float* __restrict__ smax) {
    int lane = threadIdx.x & 31;
    long e = (long)blockIdx.x * 8 + (threadIdx.x >> 5);
    if (e >= EP) return;
    int s, d;
    if (e < N_EDGES) { s = ei[e]; d = ei[N_EDGES + e]; }
    else             { s = d = (int)(e - N_EDGES); }
    float v = xl[(size_t)s * LAT + lane] + xr[(size_t)d * LAT + lane];
    v = v > 0.f ? v : NEG * v;
    v *= att[lane];
#pragma unroll
    for (int off = 16; off > 0; off >>= 1) v += __shfl_xor(v, off);
    if (lane == 0) { score[e] = v; atomicMaxF(&smax[d], v); }
}

// ---------------- L2 pass 2 ----------------
__global__ void edge_exp2(const int* __restrict__ ei, float* __restrict__ score,
                          const float* __restrict__ smax, float* __restrict__ denom) {
    long e = (long)blockIdx.x * 256 + threadIdx.x;
    if (e >= EP) return;
    int d = (e < N_EDGES) ? ei[N_EDGES + e] : (int)(e - N_EDGES);
    float ex = expf(score[e] - smax[d]);
    score[e] = ex;
    atomicAdd(&denom[d], ex);
}

// ---------------- L2 pass 3 ----------------
__global__ __launch_bounds__(256) void edge_agg2(const float* __restrict__ xl,
                                                 const int* __restrict__ ei,
                                                 const float* __restrict__ score,
                                                 const float* __restrict__ denom,
                                                 float* __restrict__ z) {
    int lane = threadIdx.x & 31;
    long e = (long)blockIdx.x * 8 + (threadIdx.x >> 5);
    if (e >= EP) return;
    int s, d;
    if (e < N_EDGES) { s = ei[e]; d = ei[N_EDGES + e]; }
    else             { s = d = (int)(e - N_EDGES); }
    float alpha = score[e] / denom[d];
    atomicAdd(&z[(size_t)d * LAT + lane], xl[(size_t)s * LAT + lane] * alpha);
}

// ---------------- node2: z += bias2 ----------------
__global__ void node_bias2(float* __restrict__ z, const float* __restrict__ b) {
    int i = blockIdx.x * 256 + threadIdx.x;
    if (i < N_NODES * LAT) z[i] += b[i & (LAT - 1)];
}

// ---------------- decode: sigmoid(<z[row], z[col]>) over original edges ----------------
__global__ __launch_bounds__(256) void decode(const float* __restrict__ z,
                                              const int* __restrict__ ei,
                                              float* __restrict__ out) {
    int lane = threadIdx.x & 31;
    long e = (long)blockIdx.x * 8 + (threadIdx.x >> 5);
    if (e >= N_EDGES) return;
    int r = ei[e], c = ei[N_EDGES + e];
    float v = z[(size_t)r * LAT + lane] * z[(size_t)c * LAT + lane];
#pragma unroll
    for (int off = 16; off > 0; off >>= 1) v += __shfl_xor(v, off);
    if (lane == 0) out[e] = 1.0f / (1.0f + expf(-v));
}

extern "C" void kernel_launch(void* const* d_in, const int* in_sizes, int n_in,
                              void* d_out, int out_size, void* d_ws, size_t ws_size,
                              hipStream_t stream) {
    const float* x    = (const float*)d_in[0];
    const int*   ei   = (const int*)d_in[1];
    const float* Wl1  = (const float*)d_in[2];
    const float* Wr1  = (const float*)d_in[3];
    const float* att1 = (const float*)d_in[4];
    const float* b1   = (const float*)d_in[5];
    const float* Wl2  = (const float*)d_in[6];
    const float* Wr2  = (const float*)d_in[7];
    const float* att2 = (const float*)d_in[8];
    const float* b2   = (const float*)d_in[9];
    float* out = (float*)d_out;

    float* ws     = (float*)d_ws;
    float* xl1    = ws;                                   // N*256
    float* buf2   = xl1 + (size_t)N_NODES * F1;           // xr1 -> out1 -> h (N*256)
    float* score1 = buf2 + (size_t)N_NODES * F1;          // EP*4
    float* smax1  = score1 + (size_t)EP * HEADS;          // N*4
    float* denom1 = smax1 + (size_t)N_NODES * HEADS;      // N*4
    // layer-2 buffers reuse the xl1 region (xl1 dead after edge_agg1)
    float* xl2    = xl1;                                  // N*32
    float* xr2    = xl2 + (size_t)N_NODES * LAT;          // N*32
    float* z      = xr2 + (size_t)N_NODES * LAT;          // N*32
    float* score2 = z + (size_t)N_NODES * LAT;            // EP
    float* smax2  = score2 + EP;                          // N
    float* denom2 = smax2 + N_NODES;                      // N

    // ---- layer 1 ----
    gemm1<<<dim3((N_NODES + 63) / 64, F1 / 64), 256, 0, stream>>>(x, Wl1, Wr1, xl1, buf2);
    init1<<<(N_NODES * HEADS + 255) / 256, 256, 0, stream>>>(smax1, denom1);
    edge_max1<<<(EP + 3) / 4, 256, 0, stream>>>(xl1, buf2, ei, att1, score1, smax1);
    // xr1 consumed; zero buf2 to become the aggregation accumulator
    hipMemsetAsync(buf2, 0, (size_t)N_NODES * F1 * sizeof(float), stream);
    edge_exp1<<<((long)EP * HEADS + 255) / 256, 256, 0, stream>>>(ei, score1, smax1, denom1);
    edge_agg1<<<(EP + 3) / 4, 256, 0, stream>>>(xl1, ei, score1, denom1, buf2);
    node_elu<<<((long)N_NODES * F1 + 255) / 256, 256, 0, stream>>>(buf2, b1);

    // ---- layer 2 ----
    gemm2<<<(N_NODES + 7) / 8, 256, 0, stream>>>(buf2, Wl2, Wr2, xl2, xr2);
    init2<<<(N_NODES + 255) / 256, 256, 0, stream>>>(smax2, denom2);
    edge_max2<<<(EP + 7) / 8, 256, 0, stream>>>(xl2, xr2, ei, att2, score2, smax2);
    hipMemsetAsync(z, 0, (size_t)N_NODES * LAT * sizeof(float), stream);
    edge_exp2<<<(EP + 255) / 256, 256, 0, stream>>>(ei, score2, smax2, denom2);
    edge_agg2<<<(EP + 7) / 8, 256, 0, stream>>>(xl2, ei, score2, denom2, z);
    node_bias2<<<(N_NODES * LAT + 255) / 256, 256, 0, stream>>>(z, b2);

    // ---- decode ----
    decode<<<(N_EDGES + 7) / 8, 256, 0, stream>>>(z, ei, out);
}

// Round 2
// 671.714 us; speedup vs baseline: 2.3916x; 2.3916x over previous
//
#include <hip/hip_runtime.h>
#include <math.h>

#define N_NODES 50000
#define N_EDGES 800000
#define EP (N_EDGES + N_NODES)   /* 850000 with self loops */
#define IN_CH 128
#define HID 64
#define HEADS 4
#define F1 (HEADS * HID)         /* 256 */
#define LAT 32
#define NEG 0.2f
#define NB_SCAN ((N_NODES + 255) / 256)   /* 196 blocks */

// ---------------- GEMM1: x(N,128) @ Wl/Wr(128,256) -> xl1, xr1 ----------------
__global__ __launch_bounds__(256) void gemm1(const float* __restrict__ x,
                                             const float* __restrict__ Wl,
                                             const float* __restrict__ Wr,
                                             float* __restrict__ xl,
                                             float* __restrict__ xr) {
    __shared__ float xs[64][132];
    __shared__ float wls[128][64];
    __shared__ float wrs[128][64];
    int t = threadIdx.x;
    int row0 = blockIdx.x * 64;
    int col0 = blockIdx.y * 64;
#pragma unroll
    for (int i = 0; i < 8; i++) {
        int f = t + i * 256;
        int r = f >> 5;
        int k4 = (f & 31) << 2;
        float4 v = make_float4(0.f, 0.f, 0.f, 0.f);
        if (row0 + r < N_NODES)
            v = *(const float4*)(x + (size_t)(row0 + r) * IN_CH + k4);
        *(float4*)&xs[r][k4] = v;
    }
#pragma unroll
    for (int i = 0; i < 8; i++) {
        int f = t + i * 256;
        int k = f >> 4;
        int c4 = (f & 15) << 2;
        *(float4*)&wls[k][c4] = *(const float4*)(Wl + (size_t)k * F1 + col0 + c4);
        *(float4*)&wrs[k][c4] = *(const float4*)(Wr + (size_t)k * F1 + col0 + c4);
    }
    __syncthreads();
    int ty = t >> 4, tx = t & 15;
    int r0 = ty * 4, c0 = tx * 4;
    float accl[4][4] = {};
    float accr[4][4] = {};
    for (int k = 0; k < 128; k++) {
        float a[4];
#pragma unroll
        for (int i = 0; i < 4; i++) a[i] = xs[r0 + i][k];
        float4 bl = *(float4*)&wls[k][c0];
        float4 br = *(float4*)&wrs[k][c0];
#pragma unroll
        for (int i = 0; i < 4; i++) {
            accl[i][0] += a[i] * bl.x; accl[i][1] += a[i] * bl.y;
            accl[i][2] += a[i] * bl.z; accl[i][3] += a[i] * bl.w;
            accr[i][0] += a[i] * br.x; accr[i][1] += a[i] * br.y;
            accr[i][2] += a[i] * br.z; accr[i][3] += a[i] * br.w;
        }
    }
#pragma unroll
    for (int i = 0; i < 4; i++) {
        int r = row0 + r0 + i;
        if (r < N_NODES) {
            *(float4*)(xl + (size_t)r * F1 + col0 + c0) =
                make_float4(accl[i][0], accl[i][1], accl[i][2], accl[i][3]);
            *(float4*)(xr + (size_t)r * F1 + col0 + c0) =
                make_float4(accr[i][0], accr[i][1], accr[i][2], accr[i][3]);
        }
    }
}

// ---------------- CSR build ----------------
__global__ void hist(const int* __restrict__ ei, int* __restrict__ deg) {
    long e = (long)blockIdx.x * 256 + threadIdx.x;
    if (e >= EP) return;
    int d = (e < N_EDGES) ? ei[N_EDGES + e] : (int)(e - N_EDGES);
    atomicAdd(&deg[d], 1);
}

__global__ void scan1(const int* __restrict__ deg, int* __restrict__ partial,
                      int* __restrict__ bsums) {
    __shared__ int tmp[256];
    int t = threadIdx.x;
    int i = blockIdx.x * 256 + t;
    tmp[t] = (i < N_NODES) ? deg[i] : 0;
    __syncthreads();
#pragma unroll
    for (int off = 1; off < 256; off <<= 1) {
        int v = (t >= off) ? tmp[t - off] : 0;
        __syncthreads();
        tmp[t] += v;
        __syncthreads();
    }
    if (i < N_NODES) partial[i] = tmp[t];
    if (t == 255) bsums[blockIdx.x] = tmp[255];
}

__global__ void scan2(int* __restrict__ bsums) {
    __shared__ int tmp[256];
    int t = threadIdx.x;
    tmp[t] = (t < NB_SCAN) ? bsums[t] : 0;
    __syncthreads();
#pragma unroll
    for (int off = 1; off < 256; off <<= 1) {
        int v = (t >= off) ? tmp[t - off] : 0;
        __syncthreads();
        tmp[t] += v;
        __syncthreads();
    }
    if (t < NB_SCAN) bsums[t] = tmp[t];
}

__global__ void scan3(const int* __restrict__ partial, const int* __restrict__ bsums,
                      const int* __restrict__ deg, int* __restrict__ row_start,
                      int* __restrict__ cur) {
    int i = blockIdx.x * 256 + threadIdx.x;
    if (i >= N_NODES) return;
    int add = (blockIdx.x > 0) ? bsums[blockIdx.x - 1] : 0;
    int excl = partial[i] + add - deg[i];
    row_start[i] = excl;
    cur[i] = excl;
}

__global__ void scatter_csr(const int* __restrict__ ei, int* __restrict__ cur,
                            int* __restrict__ srcs) {
    long e = (long)blockIdx.x * 256 + threadIdx.x;
    if (e >= EP) return;
    int s, d;
    if (e < N_EDGES) { s = ei[e]; d = ei[N_EDGES + e]; }
    else             { s = d = (int)(e - N_EDGES); }
    int pos = atomicAdd(&cur[d], 1);
    srcs[pos] = s;
}

// ------- fused L1: per-dst online-softmax aggregation + bias + ELU (in place) -------
__global__ __launch_bounds__(256) void fused_l1(const float* __restrict__ xl,
                                                float* __restrict__ xr_h,
                                                const int* __restrict__ srcs,
                                                const int* __restrict__ row_start,
                                                const int* __restrict__ deg,
                                                const float* __restrict__ att,
                                                const float* __restrict__ bias) {
    int wave = threadIdx.x >> 6;
    int lane = threadIdx.x & 63;
    int d = blockIdx.x * 4 + wave;
    if (d >= N_NODES) return;
    int c0 = lane << 2;                 // 4 channels per lane; head = lane>>4
    float4 xr4 = *(const float4*)(xr_h + (size_t)d * F1 + c0);
    float4 at4 = *(const float4*)(att + c0);
    int start = row_start[d];
    int dg = deg[d];
    float m = -3.0e38f, l = 0.f;
    float4 acc = make_float4(0.f, 0.f, 0.f, 0.f);
    for (int j = 0; j < dg; j++) {
        int s = srcs[start + j];
        float4 a = *(const float4*)(xl + (size_t)s * F1 + c0);
        float v0 = a.x + xr4.x; v0 = v0 > 0.f ? v0 : NEG * v0;
        float v1 = a.y + xr4.y; v1 = v1 > 0.f ? v1 : NEG * v1;
        float v2 = a.z + xr4.z; v2 = v2 > 0.f ? v2 : NEG * v2;
        float v3 = a.w + xr4.w; v3 = v3 > 0.f ? v3 : NEG * v3;
        float sc = v0 * at4.x + v1 * at4.y + v2 * at4.z + v3 * at4.w;
        // reduce over the 16 lanes sharing this head
        sc += __shfl_xor(sc, 1);
        sc += __shfl_xor(sc, 2);
        sc += __shfl_xor(sc, 4);
        sc += __shfl_xor(sc, 8);
        // online softmax update
        float mnew = fmaxf(m, sc);
        float scale = __expf(m - mnew);
        float ex = __expf(sc - mnew);
        l = l * scale + ex;
        acc.x = acc.x * scale + ex * a.x;
        acc.y = acc.y * scale + ex * a.y;
        acc.z = acc.z * scale + ex * a.z;
        acc.w = acc.w * scale + ex * a.w;
        m = mnew;
    }
    float inv = 1.0f / l;
    float4 b4 = *(const float4*)(bias + c0);
    float o0 = acc.x * inv + b4.x; o0 = o0 > 0.f ? o0 : expm1f(o0);
    float o1 = acc.y * inv + b4.y; o1 = o1 > 0.f ? o1 : expm1f(o1);
    float o2 = acc.z * inv + b4.z; o2 = o2 > 0.f ? o2 : expm1f(o2);
    float o3 = acc.w * inv + b4.w; o3 = o3 > 0.f ? o3 : expm1f(o3);
    *(float4*)(xr_h + (size_t)d * F1 + c0) = make_float4(o0, o1, o2, o3);
}

// ---------------- GEMM2: h(N,256) @ Wl2/Wr2(256,32) -> xl2, xr2 ----------------
__global__ __launch_bounds__(256) void gemm2(const float* __restrict__ h,
                                             const float* __restrict__ Wl,
                                             const float* __restrict__ Wr,
                                             float* __restrict__ xl2,
                                             float* __restrict__ xr2) {
    __shared__ float hs[8][256];
    int t = threadIdx.x;
    int row0 = blockIdx.x * 8;
#pragma unroll
    for (int i = 0; i < 2; i++) {
        int f = t + i * 256;
        int r = f >> 6;
        int k4 = (f & 63) << 2;
        float4 v = make_float4(0.f, 0.f, 0.f, 0.f);
        if (row0 + r < N_NODES)
            v = *(const float4*)(h + (size_t)(row0 + r) * F1 + k4);
        *(float4*)&hs[r][k4] = v;
    }
    __syncthreads();
    int c = t & 31, rl = t >> 5;
    float al = 0.f, ar = 0.f;
    for (int k = 0; k < F1; k++) {
        float hv = hs[rl][k];
        al += hv * Wl[k * LAT + c];
        ar += hv * Wr[k * LAT + c];
    }
    int r = row0 + rl;
    if (r < N_NODES) {
        xl2[(size_t)r * LAT + c] = al;
        xr2[(size_t)r * LAT + c] = ar;
    }
}

// ------- fused L2: per-dst online-softmax aggregation + bias (heads=1, 32 ch) -------
__global__ __launch_bounds__(256) void fused_l2(const float* __restrict__ xl2,
                                                const float* __restrict__ xr2,
                                                const int* __restrict__ srcs,
                                                const int* __restrict__ row_start,
                                                const int* __restrict__ deg,
                                                const float* __restrict__ att,
                                                const float* __restrict__ bias,
                                                float* __restrict__ z) {
    int sub = threadIdx.x >> 5;
    int lane = threadIdx.x & 31;
    int d = blockIdx.x * 8 + sub;
    if (d >= N_NODES) return;
    float xr = xr2[(size_t)d * LAT + lane];
    float av = att[lane];
    int start = row_start[d];
    int dg = deg[d];
    float m = -3.0e38f, l = 0.f, acc = 0.f;
    for (int j = 0; j < dg; j++) {
        int s = srcs[start + j];
        float a = xl2[(size_t)s * LAT + lane];
        float v = a + xr; v = v > 0.f ? v : NEG * v;
        float sc = v * av;
        sc += __shfl_xor(sc, 1);
        sc += __shfl_xor(sc, 2);
        sc += __shfl_xor(sc, 4);
        sc += __shfl_xor(sc, 8);
        sc += __shfl_xor(sc, 16);
        float mnew = fmaxf(m, sc);
        float scale = __expf(m - mnew);
        float ex = __expf(sc - mnew);
        l = l * scale + ex;
        acc = acc * scale + ex * a;
        m = mnew;
    }
    z[(size_t)d * LAT + lane] = acc / l + bias[lane];
}

// ---------------- decode: sigmoid(<z[row], z[col]>) over original edges ----------------
__global__ __launch_bounds__(256) void decode(const float* __restrict__ z,
                                              const int* __restrict__ ei,
                                              float* __restrict__ out) {
    int lane = threadIdx.x & 31;
    long e = (long)blockIdx.x * 8 + (threadIdx.x >> 5);
    if (e >= N_EDGES) return;
    int r = ei[e], c = ei[N_EDGES + e];
    float v = z[(size_t)r * LAT + lane] * z[(size_t)c * LAT + lane];
#pragma unroll
    for (int off = 16; off > 0; off >>= 1) v += __shfl_xor(v, off);
    if (lane == 0) out[e] = 1.0f / (1.0f + expf(-v));
}

extern "C" void kernel_launch(void* const* d_in, const int* in_sizes, int n_in,
                              void* d_out, int out_size, void* d_ws, size_t ws_size,
                              hipStream_t stream) {
    const float* x    = (const float*)d_in[0];
    const int*   ei   = (const int*)d_in[1];
    const float* Wl1  = (const float*)d_in[2];
    const float* Wr1  = (const float*)d_in[3];
    const float* att1 = (const float*)d_in[4];
    const float* b1   = (const float*)d_in[5];
    const float* Wl2  = (const float*)d_in[6];
    const float* Wr2  = (const float*)d_in[7];
    const float* att2 = (const float*)d_in[8];
    const float* b2   = (const float*)d_in[9];
    float* out = (float*)d_out;

    float* ws   = (float*)d_ws;
    float* xl1  = ws;                                  // N*256 floats (51.2 MB)
    float* xr1  = xl1 + (size_t)N_NODES * F1;          // N*256 -> becomes h in place
    int* deg       = (int*)(xr1 + (size_t)N_NODES * F1);
    int* row_start = deg + N_NODES;
    int* cur       = row_start + N_NODES;
    int* partial   = cur + N_NODES;
    int* bsums     = partial + N_NODES;
    int* srcs      = bsums + 256;                      // EP ints (3.4 MB)
    // layer-2 buffers reuse the xl1 region (dead after fused_l1)
    float* xl2 = xl1;                                  // N*32
    float* xr2 = xl2 + (size_t)N_NODES * LAT;
    float* z   = xr2 + (size_t)N_NODES * LAT;

    // ---- CSR build (graph is identical for both layers) ----
    hipMemsetAsync(deg, 0, N_NODES * sizeof(int), stream);
    gemm1<<<dim3((N_NODES + 63) / 64, F1 / 64), 256, 0, stream>>>(x, Wl1, Wr1, xl1, xr1);
    hist<<<(EP + 255) / 256, 256, 0, stream>>>(ei, deg);
    scan1<<<NB_SCAN, 256, 0, stream>>>(deg, partial, bsums);
    scan2<<<1, 256, 0, stream>>>(bsums);
    scan3<<<NB_SCAN, 256, 0, stream>>>(partial, bsums, deg, row_start, cur);
    scatter_csr<<<(EP + 255) / 256, 256, 0, stream>>>(ei, cur, srcs);

    // ---- layer 1 (fused softmax-aggregate, writes h over xr1) ----
    fused_l1<<<(N_NODES + 3) / 4, 256, 0, stream>>>(xl1, xr1, srcs, row_start, deg, att1, b1);

    // ---- layer 2 ----
    gemm2<<<(N_NODES + 7) / 8, 256, 0, stream>>>(xr1, Wl2, Wr2, xl2, xr2);
    fused_l2<<<(N_NODES + 7) / 8, 256, 0, stream>>>(xl2, xr2, srcs, row_start, deg, att2, b2, z);

    // ---- decode ----
    decode<<<(N_EDGES + 7) / 8, 256, 0, stream>>>(z, ei, out);
}

// Round 3
// 578.717 us; speedup vs baseline: 2.7760x; 1.1607x over previous
//
#include <hip/hip_runtime.h>
#include <math.h>

#define N_NODES 50000
#define N_EDGES 800000
#define EP (N_EDGES + N_NODES)   /* 850000 with self loops */
#define IN_CH 128
#define HID 64
#define HEADS 4
#define F1 (HEADS * HID)         /* 256 */
#define LAT 32
#define NEG 0.2f
#define NB_SCAN ((N_NODES + 255) / 256)   /* 196 blocks */
#define KB 32                     /* gemm1 k-chunk */

// ---------------- GEMM1: x(N,128) @ Wl/Wr(128,256) -> xl1, xr1 ----------------
// K-chunked: LDS 25.3 KB (was 97 KB -> 1 block/CU, occupancy 10.5%).
// launch_bounds(256,4): 4 waves/EU -> 4 blocks/CU, VGPR cap 128.
__global__ __launch_bounds__(256, 4) void gemm1(const float* __restrict__ x,
                                                const float* __restrict__ Wl,
                                                const float* __restrict__ Wr,
                                                float* __restrict__ xl,
                                                float* __restrict__ xr) {
    __shared__ float xsT[KB][68];    // k-major; stride 68 floats = 272 B (16B-aligned)
    __shared__ float wls[KB][64];
    __shared__ float wrs[KB][64];
    int t = threadIdx.x;
    int row0 = blockIdx.x * 64;
    int col0 = blockIdx.y * 64;
    int ty = t >> 4, tx = t & 15;
    int r0 = ty * 4, c0 = tx * 4;
    float accl[4][4] = {};
    float accr[4][4] = {};
    for (int k0 = 0; k0 < IN_CH; k0 += KB) {
        // stage x chunk (64 rows x 32 k), transpose to k-major
#pragma unroll
        for (int i = 0; i < 2; i++) {
            int f = t + i * 256;          // float4 idx 0..511
            int r = f >> 3;               // 0..63
            int kk = (f & 7) << 2;        // 0,4,...,28
            float4 v = make_float4(0.f, 0.f, 0.f, 0.f);
            if (row0 + r < N_NODES)
                v = *(const float4*)(x + (size_t)(row0 + r) * IN_CH + k0 + kk);
            xsT[kk + 0][r] = v.x;
            xsT[kk + 1][r] = v.y;
            xsT[kk + 2][r] = v.z;
            xsT[kk + 3][r] = v.w;
        }
        // stage W chunks (32 k x 64 c each)
#pragma unroll
        for (int i = 0; i < 2; i++) {
            int f = t + i * 256;          // float4 idx 0..511
            int k = f >> 4;               // 0..31
            int c4 = (f & 15) << 2;
            *(float4*)&wls[k][c4] = *(const float4*)(Wl + (size_t)(k0 + k) * F1 + col0 + c4);
            *(float4*)&wrs[k][c4] = *(const float4*)(Wr + (size_t)(k0 + k) * F1 + col0 + c4);
        }
        __syncthreads();
#pragma unroll 8
        for (int k = 0; k < KB; k++) {
            float4 a4 = *(float4*)&xsT[k][r0];   // ds_read_b128, 16-lane broadcast
            float4 bl = *(float4*)&wls[k][c0];
            float4 br = *(float4*)&wrs[k][c0];
            float a[4] = {a4.x, a4.y, a4.z, a4.w};
#pragma unroll
            for (int i = 0; i < 4; i++) {
                accl[i][0] += a[i] * bl.x; accl[i][1] += a[i] * bl.y;
                accl[i][2] += a[i] * bl.z; accl[i][3] += a[i] * bl.w;
                accr[i][0] += a[i] * br.x; accr[i][1] += a[i] * br.y;
                accr[i][2] += a[i] * br.z; accr[i][3] += a[i] * br.w;
            }
        }
        __syncthreads();
    }
#pragma unroll
    for (int i = 0; i < 4; i++) {
        int r = row0 + r0 + i;
        if (r < N_NODES) {
            *(float4*)(xl + (size_t)r * F1 + col0 + c0) =
                make_float4(accl[i][0], accl[i][1], accl[i][2], accl[i][3]);
            *(float4*)(xr + (size_t)r * F1 + col0 + c0) =
                make_float4(accr[i][0], accr[i][1], accr[i][2], accr[i][3]);
        }
    }
}

// ---------------- CSR build ----------------
__global__ void hist(const int* __restrict__ ei, int* __restrict__ deg) {
    long e = (long)blockIdx.x * 256 + threadIdx.x;
    if (e >= EP) return;
    int d = (e < N_EDGES) ? ei[N_EDGES + e] : (int)(e - N_EDGES);
    atomicAdd(&deg[d], 1);
}

__global__ void scan1(const int* __restrict__ deg, int* __restrict__ partial,
                      int* __restrict__ bsums) {
    __shared__ int tmp[256];
    int t = threadIdx.x;
    int i = blockIdx.x * 256 + t;
    tmp[t] = (i < N_NODES) ? deg[i] : 0;
    __syncthreads();
#pragma unroll
    for (int off = 1; off < 256; off <<= 1) {
        int v = (t >= off) ? tmp[t - off] : 0;
        __syncthreads();
        tmp[t] += v;
        __syncthreads();
    }
    if (i < N_NODES) partial[i] = tmp[t];
    if (t == 255) bsums[blockIdx.x] = tmp[255];
}

__global__ void scan2(int* __restrict__ bsums) {
    __shared__ int tmp[256];
    int t = threadIdx.x;
    tmp[t] = (t < NB_SCAN) ? bsums[t] : 0;
    __syncthreads();
#pragma unroll
    for (int off = 1; off < 256; off <<= 1) {
        int v = (t >= off) ? tmp[t - off] : 0;
        __syncthreads();
        tmp[t] += v;
        __syncthreads();
    }
    if (t < NB_SCAN) bsums[t] = tmp[t];
}

__global__ void scan3(const int* __restrict__ partial, const int* __restrict__ bsums,
                      const int* __restrict__ deg, int* __restrict__ row_start,
                      int* __restrict__ cur) {
    int i = blockIdx.x * 256 + threadIdx.x;
    if (i >= N_NODES) return;
    int add = (blockIdx.x > 0) ? bsums[blockIdx.x - 1] : 0;
    int excl = partial[i] + add - deg[i];
    row_start[i] = excl;
    cur[i] = excl;
}

__global__ void scatter_csr(const int* __restrict__ ei, int* __restrict__ cur,
                            int* __restrict__ srcs) {
    long e = (long)blockIdx.x * 256 + threadIdx.x;
    if (e >= EP) return;
    int s, d;
    if (e < N_EDGES) { s = ei[e]; d = ei[N_EDGES + e]; }
    else             { s = d = (int)(e - N_EDGES); }
    int pos = atomicAdd(&cur[d], 1);
    srcs[pos] = s;
}

// ------- fused L1: per-dst online-softmax aggregation + bias + ELU (in place) -------
__global__ __launch_bounds__(256) void fused_l1(const float* __restrict__ xl,
                                                float* __restrict__ xr_h,
                                                const int* __restrict__ srcs,
                                                const int* __restrict__ row_start,
                                                const int* __restrict__ deg,
                                                const float* __restrict__ att,
                                                const float* __restrict__ bias) {
    int wave = threadIdx.x >> 6;
    int lane = threadIdx.x & 63;
    int d = blockIdx.x * 4 + wave;
    if (d >= N_NODES) return;
    int c0 = lane << 2;                 // 4 channels per lane; head = lane>>4
    float4 xr4 = *(const float4*)(xr_h + (size_t)d * F1 + c0);
    float4 at4 = *(const float4*)(att + c0);
    int start = row_start[d];
    int dg = deg[d];
    float m = -3.0e38f, l = 0.f;
    float4 acc = make_float4(0.f, 0.f, 0.f, 0.f);
    for (int j = 0; j < dg; j++) {
        int s = srcs[start + j];
        float4 a = *(const float4*)(xl + (size_t)s * F1 + c0);
        float v0 = a.x + xr4.x; v0 = v0 > 0.f ? v0 : NEG * v0;
        float v1 = a.y + xr4.y; v1 = v1 > 0.f ? v1 : NEG * v1;
        float v2 = a.z + xr4.z; v2 = v2 > 0.f ? v2 : NEG * v2;
        float v3 = a.w + xr4.w; v3 = v3 > 0.f ? v3 : NEG * v3;
        float sc = v0 * at4.x + v1 * at4.y + v2 * at4.z + v3 * at4.w;
        sc += __shfl_xor(sc, 1);
        sc += __shfl_xor(sc, 2);
        sc += __shfl_xor(sc, 4);
        sc += __shfl_xor(sc, 8);
        float mnew = fmaxf(m, sc);
        float scale = __expf(m - mnew);
        float ex = __expf(sc - mnew);
        l = l * scale + ex;
        acc.x = acc.x * scale + ex * a.x;
        acc.y = acc.y * scale + ex * a.y;
        acc.z = acc.z * scale + ex * a.z;
        acc.w = acc.w * scale + ex * a.w;
        m = mnew;
    }
    float inv = 1.0f / l;
    float4 b4 = *(const float4*)(bias + c0);
    float o0 = acc.x * inv + b4.x; o0 = o0 > 0.f ? o0 : expm1f(o0);
    float o1 = acc.y * inv + b4.y; o1 = o1 > 0.f ? o1 : expm1f(o1);
    float o2 = acc.z * inv + b4.z; o2 = o2 > 0.f ? o2 : expm1f(o2);
    float o3 = acc.w * inv + b4.w; o3 = o3 > 0.f ? o3 : expm1f(o3);
    *(float4*)(xr_h + (size_t)d * F1 + c0) = make_float4(o0, o1, o2, o3);
}

// ---------------- GEMM2: h(N,256) @ Wl2/Wr2(256,32) -> xl2, xr2 ----------------
// 16 rows/block, 2 rows/thread: halves W re-fetch per output row.
__global__ __launch_bounds__(256) void gemm2(const float* __restrict__ h,
                                             const float* __restrict__ Wl,
                                             const float* __restrict__ Wr,
                                             float* __restrict__ xl2,
                                             float* __restrict__ xr2) {
    __shared__ float hs[16][256];
    int t = threadIdx.x;
    int row0 = blockIdx.x * 16;
#pragma unroll
    for (int i = 0; i < 4; i++) {
        int f = t + i * 256;              // float4 idx 0..1023
        int r = f >> 6;
        int k4 = (f & 63) << 2;
        float4 v = make_float4(0.f, 0.f, 0.f, 0.f);
        if (row0 + r < N_NODES)
            v = *(const float4*)(h + (size_t)(row0 + r) * F1 + k4);
        *(float4*)&hs[r][k4] = v;
    }
    __syncthreads();
    int c = t & 31, rl = t >> 5;          // rl 0..7; rows rl and rl+8
    float al0 = 0.f, ar0 = 0.f, al1 = 0.f, ar1 = 0.f;
    for (int k = 0; k < F1; k++) {
        float wl = Wl[k * LAT + c];
        float wr = Wr[k * LAT + c];
        float h0 = hs[rl][k];
        float h1 = hs[rl + 8][k];
        al0 += h0 * wl; ar0 += h0 * wr;
        al1 += h1 * wl; ar1 += h1 * wr;
    }
    int r = row0 + rl;
    if (r < N_NODES) {
        xl2[(size_t)r * LAT + c] = al0;
        xr2[(size_t)r * LAT + c] = ar0;
    }
    if (r + 8 < N_NODES) {
        xl2[(size_t)(r + 8) * LAT + c] = al1;
        xr2[(size_t)(r + 8) * LAT + c] = ar1;
    }
}

// ------- fused L2: per-dst online-softmax aggregation + bias (heads=1, 32 ch) -------
__global__ __launch_bounds__(256) void fused_l2(const float* __restrict__ xl2,
                                                const float* __restrict__ xr2,
                                                const int* __restrict__ srcs,
                                                const int* __restrict__ row_start,
                                                const int* __restrict__ deg,
                                                const float* __restrict__ att,
                                                const float* __restrict__ bias,
                                                float* __restrict__ z) {
    int sub = threadIdx.x >> 5;
    int lane = threadIdx.x & 31;
    int d = blockIdx.x * 8 + sub;
    if (d >= N_NODES) return;
    float xr = xr2[(size_t)d * LAT + lane];
    float av = att[lane];
    int start = row_start[d];
    int dg = deg[d];
    float m = -3.0e38f, l = 0.f, acc = 0.f;
    for (int j = 0; j < dg; j++) {
        int s = srcs[start + j];
        float a = xl2[(size_t)s * LAT + lane];
        float v = a + xr; v = v > 0.f ? v : NEG * v;
        float sc = v * av;
        sc += __shfl_xor(sc, 1);
        sc += __shfl_xor(sc, 2);
        sc += __shfl_xor(sc, 4);
        sc += __shfl_xor(sc, 8);
        sc += __shfl_xor(sc, 16);
        float mnew = fmaxf(m, sc);
        float scale = __expf(m - mnew);
        float ex = __expf(sc - mnew);
        l = l * scale + ex;
        acc = acc * scale + ex * a;
        m = mnew;
    }
    z[(size_t)d * LAT + lane] = acc / l + bias[lane];
}

// ---------------- decode: sigmoid(<z[row], z[col]>) over original edges ----------------
__global__ __launch_bounds__(256) void decode(const float* __restrict__ z,
                                              const int* __restrict__ ei,
                                              float* __restrict__ out) {
    int lane = threadIdx.x & 31;
    long e = (long)blockIdx.x * 8 + (threadIdx.x >> 5);
    if (e >= N_EDGES) return;
    int r = ei[e], c = ei[N_EDGES + e];
    float v = z[(size_t)r * LAT + lane] * z[(size_t)c * LAT + lane];
#pragma unroll
    for (int off = 16; off > 0; off >>= 1) v += __shfl_xor(v, off);
    if (lane == 0) out[e] = 1.0f / (1.0f + expf(-v));
}

extern "C" void kernel_launch(void* const* d_in, const int* in_sizes, int n_in,
                              void* d_out, int out_size, void* d_ws, size_t ws_size,
                              hipStream_t stream) {
    const float* x    = (const float*)d_in[0];
    const int*   ei   = (const int*)d_in[1];
    const float* Wl1  = (const float*)d_in[2];
    const float* Wr1  = (const float*)d_in[3];
    const float* att1 = (const float*)d_in[4];
    const float* b1   = (const float*)d_in[5];
    const float* Wl2  = (const float*)d_in[6];
    const float* Wr2  = (const float*)d_in[7];
    const float* att2 = (const float*)d_in[8];
    const float* b2   = (const float*)d_in[9];
    float* out = (float*)d_out;

    float* ws   = (float*)d_ws;
    float* xl1  = ws;                                  // N*256 floats (51.2 MB)
    float* xr1  = xl1 + (size_t)N_NODES * F1;          // N*256 -> becomes h in place
    int* deg       = (int*)(xr1 + (size_t)N_NODES * F1);
    int* row_start = deg + N_NODES;
    int* cur       = row_start + N_NODES;
    int* partial   = cur + N_NODES;
    int* bsums     = partial + N_NODES;
    int* srcs      = bsums + 256;                      // EP ints (3.4 MB)
    // layer-2 buffers reuse the xl1 region (dead after fused_l1)
    float* xl2 = xl1;                                  // N*32
    float* xr2 = xl2 + (size_t)N_NODES * LAT;
    float* z   = xr2 + (size_t)N_NODES * LAT;

    // ---- CSR build (graph is identical for both layers) ----
    hipMemsetAsync(deg, 0, N_NODES * sizeof(int), stream);
    gemm1<<<dim3((N_NODES + 63) / 64, F1 / 64), 256, 0, stream>>>(x, Wl1, Wr1, xl1, xr1);
    hist<<<(EP + 255) / 256, 256, 0, stream>>>(ei, deg);
    scan1<<<NB_SCAN, 256, 0, stream>>>(deg, partial, bsums);
    scan2<<<1, 256, 0, stream>>>(bsums);
    scan3<<<NB_SCAN, 256, 0, stream>>>(partial, bsums, deg, row_start, cur);
    scatter_csr<<<(EP + 255) / 256, 256, 0, stream>>>(ei, cur, srcs);

    // ---- layer 1 (fused softmax-aggregate, writes h over xr1) ----
    fused_l1<<<(N_NODES + 3) / 4, 256, 0, stream>>>(xl1, xr1, srcs, row_start, deg, att1, b1);

    // ---- layer 2 ----
    gemm2<<<(N_NODES + 15) / 16, 256, 0, stream>>>(xr1, Wl2, Wr2, xl2, xr2);
    fused_l2<<<(N_NODES + 7) / 8, 256, 0, stream>>>(xl2, xr2, srcs, row_start, deg, att2, b2, z);

    // ---- decode ----
    decode<<<(N_EDGES + 7) / 8, 256, 0, stream>>>(z, ei, out);
}

// Round 4
// 510.614 us; speedup vs baseline: 3.1462x; 1.1334x over previous
//
#include <hip/hip_runtime.h>
#include <math.h>

#define N_NODES 50000
#define N_EDGES 800000
#define EP (N_EDGES + N_NODES)   /* 850000 with self loops */
#define IN_CH 128
#define HID 64
#define HEADS 4
#define F1 (HEADS * HID)         /* 256 */
#define LAT 32
#define NEG 0.2f
#define NB_SCAN ((N_NODES + 255) / 256)   /* 196 blocks */
#define KB 32                     /* gemm1 k-chunk */

__device__ __forceinline__ unsigned short f2bf(float f) {
    unsigned int x = __float_as_uint(f);
    x += 0x7fffu + ((x >> 16) & 1u);       // round-to-nearest-even
    return (unsigned short)(x >> 16);
}
__device__ __forceinline__ float bf2f(unsigned short u) {
    return __uint_as_float(((unsigned int)u) << 16);
}

// ------- GEMM1: x(N,128) @ Wl/Wr(128,256) -> xlh (bf16 gather payload), xr (fp32) -------
__global__ __launch_bounds__(256, 4) void gemm1(const float* __restrict__ x,
                                                const float* __restrict__ Wl,
                                                const float* __restrict__ Wr,
                                                unsigned short* __restrict__ xlh,
                                                float* __restrict__ xr) {
    __shared__ float xsT[KB][68];
    __shared__ float wls[KB][64];
    __shared__ float wrs[KB][64];
    int t = threadIdx.x;
    int row0 = blockIdx.x * 64;
    int col0 = blockIdx.y * 64;
    int ty = t >> 4, tx = t & 15;
    int r0 = ty * 4, c0 = tx * 4;
    float accl[4][4] = {};
    float accr[4][4] = {};
    for (int k0 = 0; k0 < IN_CH; k0 += KB) {
#pragma unroll
        for (int i = 0; i < 2; i++) {
            int f = t + i * 256;
            int r = f >> 3;
            int kk = (f & 7) << 2;
            float4 v = make_float4(0.f, 0.f, 0.f, 0.f);
            if (row0 + r < N_NODES)
                v = *(const float4*)(x + (size_t)(row0 + r) * IN_CH + k0 + kk);
            xsT[kk + 0][r] = v.x;
            xsT[kk + 1][r] = v.y;
            xsT[kk + 2][r] = v.z;
            xsT[kk + 3][r] = v.w;
        }
#pragma unroll
        for (int i = 0; i < 2; i++) {
            int f = t + i * 256;
            int k = f >> 4;
            int c4 = (f & 15) << 2;
            *(float4*)&wls[k][c4] = *(const float4*)(Wl + (size_t)(k0 + k) * F1 + col0 + c4);
            *(float4*)&wrs[k][c4] = *(const float4*)(Wr + (size_t)(k0 + k) * F1 + col0 + c4);
        }
        __syncthreads();
#pragma unroll 8
        for (int k = 0; k < KB; k++) {
            float4 a4 = *(float4*)&xsT[k][r0];
            float4 bl = *(float4*)&wls[k][c0];
            float4 br = *(float4*)&wrs[k][c0];
            float a[4] = {a4.x, a4.y, a4.z, a4.w};
#pragma unroll
            for (int i = 0; i < 4; i++) {
                accl[i][0] += a[i] * bl.x; accl[i][1] += a[i] * bl.y;
                accl[i][2] += a[i] * bl.z; accl[i][3] += a[i] * bl.w;
                accr[i][0] += a[i] * br.x; accr[i][1] += a[i] * br.y;
                accr[i][2] += a[i] * br.z; accr[i][3] += a[i] * br.w;
            }
        }
        __syncthreads();
    }
#pragma unroll
    for (int i = 0; i < 4; i++) {
        int r = row0 + r0 + i;
        if (r < N_NODES) {
            *(float4*)(xr + (size_t)r * F1 + col0 + c0) =
                make_float4(accr[i][0], accr[i][1], accr[i][2], accr[i][3]);
            ushort4 u;
            u.x = f2bf(accl[i][0]); u.y = f2bf(accl[i][1]);
            u.z = f2bf(accl[i][2]); u.w = f2bf(accl[i][3]);
            *(ushort4*)(xlh + (size_t)r * F1 + col0 + c0) = u;
        }
    }
}

// ---------------- CSR build ----------------
__global__ void hist(const int* __restrict__ ei, int* __restrict__ deg) {
    long e = (long)blockIdx.x * 256 + threadIdx.x;
    if (e >= EP) return;
    int d = (e < N_EDGES) ? ei[N_EDGES + e] : (int)(e - N_EDGES);
    atomicAdd(&deg[d], 1);
}

__global__ void scan1(const int* __restrict__ deg, int* __restrict__ partial,
                      int* __restrict__ bsums) {
    __shared__ int tmp[256];
    int t = threadIdx.x;
    int i = blockIdx.x * 256 + t;
    tmp[t] = (i < N_NODES) ? deg[i] : 0;
    __syncthreads();
#pragma unroll
    for (int off = 1; off < 256; off <<= 1) {
        int v = (t >= off) ? tmp[t - off] : 0;
        __syncthreads();
        tmp[t] += v;
        __syncthreads();
    }
    if (i < N_NODES) partial[i] = tmp[t];
    if (t == 255) bsums[blockIdx.x] = tmp[255];
}

__global__ void scan2(int* __restrict__ bsums) {
    __shared__ int tmp[256];
    int t = threadIdx.x;
    tmp[t] = (t < NB_SCAN) ? bsums[t] : 0;
    __syncthreads();
#pragma unroll
    for (int off = 1; off < 256; off <<= 1) {
        int v = (t >= off) ? tmp[t - off] : 0;
        __syncthreads();
        tmp[t] += v;
        __syncthreads();
    }
    if (t < NB_SCAN) bsums[t] = tmp[t];
}

__global__ void scan3(const int* __restrict__ partial, const int* __restrict__ bsums,
                      const int* __restrict__ deg, int* __restrict__ row_start,
                      int* __restrict__ cur) {
    int i = blockIdx.x * 256 + threadIdx.x;
    if (i >= N_NODES) return;
    int add = (blockIdx.x > 0) ? bsums[blockIdx.x - 1] : 0;
    int excl = partial[i] + add - deg[i];
    row_start[i] = excl;
    cur[i] = excl;
}

__global__ void scatter_csr(const int* __restrict__ ei, int* __restrict__ cur,
                            int* __restrict__ srcs) {
    long e = (long)blockIdx.x * 256 + threadIdx.x;
    if (e >= EP) return;
    int s, d;
    if (e < N_EDGES) { s = ei[e]; d = ei[N_EDGES + e]; }
    else             { s = d = (int)(e - N_EDGES); }
    int pos = atomicAdd(&cur[d], 1);
    srcs[pos] = s;
}

// ------- fused L1: per-dst online-softmax aggregation + bias + ELU (in place) -------
// bf16 gather payload + depth-2 software pipeline on the srcs->row load chain.
__global__ __launch_bounds__(256) void fused_l1(const unsigned short* __restrict__ xlh,
                                                float* __restrict__ xr_h,
                                                const int* __restrict__ srcs,
                                                const int* __restrict__ row_start,
                                                const int* __restrict__ deg,
                                                const float* __restrict__ att,
                                                const float* __restrict__ bias) {
    int wave = threadIdx.x >> 6;
    int lane = threadIdx.x & 63;
    int d = blockIdx.x * 4 + wave;
    if (d >= N_NODES) return;
    int c0 = lane << 2;                 // 4 channels per lane; head = lane>>4
    float4 xr4 = *(const float4*)(xr_h + (size_t)d * F1 + c0);
    float4 at4 = *(const float4*)(att + c0);
    int start = row_start[d];
    int dg = deg[d];
    float m = -3.0e38f, l = 0.f;
    float4 acc = make_float4(0.f, 0.f, 0.f, 0.f);
    // pipeline prologue
    int sB = srcs[start];
    ushort4 raw = *(const ushort4*)(xlh + (size_t)sB * F1 + c0);
    sB = (dg > 1) ? srcs[start + 1] : 0;
    for (int j = 0; j < dg; j++) {
        ushort4 cr = raw;
        if (j + 1 < dg) raw = *(const ushort4*)(xlh + (size_t)sB * F1 + c0);
        if (j + 2 < dg) sB = srcs[start + j + 2];
        float ax = bf2f(cr.x), ay = bf2f(cr.y), az = bf2f(cr.z), aw = bf2f(cr.w);
        float v0 = ax + xr4.x; v0 = v0 > 0.f ? v0 : NEG * v0;
        float v1 = ay + xr4.y; v1 = v1 > 0.f ? v1 : NEG * v1;
        float v2 = az + xr4.z; v2 = v2 > 0.f ? v2 : NEG * v2;
        float v3 = aw + xr4.w; v3 = v3 > 0.f ? v3 : NEG * v3;
        float sc = v0 * at4.x + v1 * at4.y + v2 * at4.z + v3 * at4.w;
        sc += __shfl_xor(sc, 1);
        sc += __shfl_xor(sc, 2);
        sc += __shfl_xor(sc, 4);
        sc += __shfl_xor(sc, 8);
        float mnew = fmaxf(m, sc);
        float scale = __expf(m - mnew);
        float ex = __expf(sc - mnew);
        l = l * scale + ex;
        acc.x = acc.x * scale + ex * ax;
        acc.y = acc.y * scale + ex * ay;
        acc.z = acc.z * scale + ex * az;
        acc.w = acc.w * scale + ex * aw;
        m = mnew;
    }
    float inv = 1.0f / l;
    float4 b4 = *(const float4*)(bias + c0);
    float o0 = acc.x * inv + b4.x; o0 = o0 > 0.f ? o0 : expm1f(o0);
    float o1 = acc.y * inv + b4.y; o1 = o1 > 0.f ? o1 : expm1f(o1);
    float o2 = acc.z * inv + b4.z; o2 = o2 > 0.f ? o2 : expm1f(o2);
    float o3 = acc.w * inv + b4.w; o3 = o3 > 0.f ? o3 : expm1f(o3);
    *(float4*)(xr_h + (size_t)d * F1 + c0) = make_float4(o0, o1, o2, o3);
}

// ---------------- GEMM2: h(N,256) @ Wl2/Wr2(256,32) -> xl2, xr2 ----------------
__global__ __launch_bounds__(256) void gemm2(const float* __restrict__ h,
                                             const float* __restrict__ Wl,
                                             const float* __restrict__ Wr,
                                             float* __restrict__ xl2,
                                             float* __restrict__ xr2) {
    __shared__ float hs[16][256];
    int t = threadIdx.x;
    int row0 = blockIdx.x * 16;
#pragma unroll
    for (int i = 0; i < 4; i++) {
        int f = t + i * 256;
        int r = f >> 6;
        int k4 = (f & 63) << 2;
        float4 v = make_float4(0.f, 0.f, 0.f, 0.f);
        if (row0 + r < N_NODES)
            v = *(const float4*)(h + (size_t)(row0 + r) * F1 + k4);
        *(float4*)&hs[r][k4] = v;
    }
    __syncthreads();
    int c = t & 31, rl = t >> 5;
    float al0 = 0.f, ar0 = 0.f, al1 = 0.f, ar1 = 0.f;
    for (int k = 0; k < F1; k++) {
        float wl = Wl[k * LAT + c];
        float wr = Wr[k * LAT + c];
        float h0 = hs[rl][k];
        float h1 = hs[rl + 8][k];
        al0 += h0 * wl; ar0 += h0 * wr;
        al1 += h1 * wl; ar1 += h1 * wr;
    }
    int r = row0 + rl;
    if (r < N_NODES) {
        xl2[(size_t)r * LAT + c] = al0;
        xr2[(size_t)r * LAT + c] = ar0;
    }
    if (r + 8 < N_NODES) {
        xl2[(size_t)(r + 8) * LAT + c] = al1;
        xr2[(size_t)(r + 8) * LAT + c] = ar1;
    }
}

// ------- fused L2: per-dst online-softmax aggregation + bias (heads=1, 32 ch) -------
__global__ __launch_bounds__(256) void fused_l2(const float* __restrict__ xl2,
                                                const float* __restrict__ xr2,
                                                const int* __restrict__ srcs,
                                                const int* __restrict__ row_start,
                                                const int* __restrict__ deg,
                                                const float* __restrict__ att,
                                                const float* __restrict__ bias,
                                                float* __restrict__ z) {
    int sub = threadIdx.x >> 5;
    int lane = threadIdx.x & 31;
    int d = blockIdx.x * 8 + sub;
    if (d >= N_NODES) return;
    float xr = xr2[(size_t)d * LAT + lane];
    float av = att[lane];
    int start = row_start[d];
    int dg = deg[d];
    float m = -3.0e38f, l = 0.f, acc = 0.f;
    int sB = srcs[start];
    float a_next = xl2[(size_t)sB * LAT + lane];
    sB = (dg > 1) ? srcs[start + 1] : 0;
    for (int j = 0; j < dg; j++) {
        float a = a_next;
        if (j + 1 < dg) a_next = xl2[(size_t)sB * LAT + lane];
        if (j + 2 < dg) sB = srcs[start + j + 2];
        float v = a + xr; v = v > 0.f ? v : NEG * v;
        float sc = v * av;
        sc += __shfl_xor(sc, 1);
        sc += __shfl_xor(sc, 2);
        sc += __shfl_xor(sc, 4);
        sc += __shfl_xor(sc, 8);
        sc += __shfl_xor(sc, 16);
        float mnew = fmaxf(m, sc);
        float scale = __expf(m - mnew);
        float ex = __expf(sc - mnew);
        l = l * scale + ex;
        acc = acc * scale + ex * a;
        m = mnew;
    }
    z[(size_t)d * LAT + lane] = acc / l + bias[lane];
}

// ---------------- decode: sigmoid(<z[row], z[col]>) over original edges ----------------
__global__ __launch_bounds__(256) void decode(const float* __restrict__ z,
                                              const int* __restrict__ ei,
                                              float* __restrict__ out) {
    int lane = threadIdx.x & 31;
    long e = (long)blockIdx.x * 8 + (threadIdx.x >> 5);
    if (e >= N_EDGES) return;
    int r = ei[e], c = ei[N_EDGES + e];
    float v = z[(size_t)r * LAT + lane] * z[(size_t)c * LAT + lane];
#pragma unroll
    for (int off = 16; off > 0; off >>= 1) v += __shfl_xor(v, off);
    if (lane == 0) out[e] = 1.0f / (1.0f + expf(-v));
}

extern "C" void kernel_launch(void* const* d_in, const int* in_sizes, int n_in,
                              void* d_out, int out_size, void* d_ws, size_t ws_size,
                              hipStream_t stream) {
    const float* x    = (const float*)d_in[0];
    const int*   ei   = (const int*)d_in[1];
    const float* Wl1  = (const float*)d_in[2];
    const float* Wr1  = (const float*)d_in[3];
    const float* att1 = (const float*)d_in[4];
    const float* b1   = (const float*)d_in[5];
    const float* Wl2  = (const float*)d_in[6];
    const float* Wr2  = (const float*)d_in[7];
    const float* att2 = (const float*)d_in[8];
    const float* b2   = (const float*)d_in[9];
    float* out = (float*)d_out;

    float* ws   = (float*)d_ws;
    float* xr1  = ws;                                  // N*256 fp32 -> becomes h in place
    unsigned short* xlh = (unsigned short*)(xr1 + (size_t)N_NODES * F1);  // N*256 bf16
    int* deg       = (int*)(xlh + (size_t)N_NODES * F1);
    int* row_start = deg + N_NODES;
    int* cur       = row_start + N_NODES;
    int* partial   = cur + N_NODES;
    int* bsums     = partial + N_NODES;
    int* srcs      = bsums + 256;                      // EP ints (3.4 MB)
    // layer-2 buffers reuse the xlh region (dead after fused_l1): need 19.2 MB <= 25.6 MB
    float* xl2 = (float*)xlh;                          // N*32
    float* xr2 = xl2 + (size_t)N_NODES * LAT;
    float* z   = xr2 + (size_t)N_NODES * LAT;

    // ---- CSR build (graph is identical for both layers) ----
    hipMemsetAsync(deg, 0, N_NODES * sizeof(int), stream);
    gemm1<<<dim3((N_NODES + 63) / 64, F1 / 64), 256, 0, stream>>>(x, Wl1, Wr1, xlh, xr1);
    hist<<<(EP + 255) / 256, 256, 0, stream>>>(ei, deg);
    scan1<<<NB_SCAN, 256, 0, stream>>>(deg, partial, bsums);
    scan2<<<1, 256, 0, stream>>>(bsums);
    scan3<<<NB_SCAN, 256, 0, stream>>>(partial, bsums, deg, row_start, cur);
    scatter_csr<<<(EP + 255) / 256, 256, 0, stream>>>(ei, cur, srcs);

    // ---- layer 1 (fused softmax-aggregate, writes h over xr1) ----
    fused_l1<<<(N_NODES + 3) / 4, 256, 0, stream>>>(xlh, xr1, srcs, row_start, deg, att1, b1);

    // ---- layer 2 ----
    gemm2<<<(N_NODES + 15) / 16, 256, 0, stream>>>(xr1, Wl2, Wr2, xl2, xr2);
    fused_l2<<<(N_NODES + 7) / 8, 256, 0, stream>>>(xl2, xr2, srcs, row_start, deg, att2, b2, z);

    // ---- decode ----
    decode<<<(N_EDGES + 7) / 8, 256, 0, stream>>>(z, ei, out);
}